// Round 20
// baseline (210.429 us; speedup 1.0000x reference)
//
#include <hip/hip_runtime.h>

typedef __attribute__((ext_vector_type(8)))  short s8b;    // 8 x bf16
typedef __attribute__((ext_vector_type(16))) float f32x16; // mfma C/D
typedef __attribute__((ext_vector_type(4)))  uint  uint4v;
typedef __attribute__((ext_vector_type(2)))  float pkf;    // packed f32 pair
typedef uint __attribute__((may_alias)) uint_ma;

static constexpr int   kBatch    = 2097152;
static constexpr float kActScale = 1.0f / 12.0f;
static constexpr float kAct2     = 1.0f / 6.0f;   // 2*ACT_SCALE

// fp32 table: [0,32) aout ; [32] cref
__device__ float g_tab[40];
// Weight A-frag tables, per matvec m: lane l holds W_m[row=l&31][j=16c+8*(l>>5)+b]
__device__ __attribute__((aligned(16))) ushort g_wt[4][2][2][64][8];
// Pair-transposed preact tables: {w1_u0,w1_u1, w2_u0,w2_u1, b_u0,b_u1, 0,0}
__device__ __attribute__((aligned(16))) float g_pA[2][2][4][8];  // W1/b1 (stage A, j-layout)
__device__ __attribute__((aligned(16))) float g_pp[2][2][8][8];  // [0]=Wc0/bc0, [1]=Wc1/bc1 (OFF-layout)

__device__ __forceinline__ float rcp_f(float x) { return __fdividef(1.0f, x); }
__device__ __forceinline__ float sp_only(float x) {
    float e = __expf(-fabsf(x));
    return fmaxf(x, 0.0f) + __logf(1.0f + e);
}
__device__ __forceinline__ float sig_only(float x) {
    float e = __expf(-fabsf(x));
    float r = rcp_f(1.0f + e);
    return (x >= 0.0f) ? r : e * r;
}
__device__ __forceinline__ float sp_sig(float x, float& sig) {
    float e  = __expf(-fabsf(x));
    float oe = 1.0f + e;
    float r  = rcp_f(oe);
    sig = (x >= 0.0f) ? r : e * r;
    return fmaxf(x, 0.0f) + __logf(oe);
}

__device__ __forceinline__ uint  bf16u(float x) {
    uint u = __float_as_uint(x);
    return (u + 0x7FFFu + ((u >> 16) & 1u)) >> 16;      // RNE
}
__device__ __forceinline__ float bf16f(uint h) { return __uint_as_float(h << 16); }
__device__ __forceinline__ uint cvt_pk_bf16(float lo, float hi) {
    uint r;
    asm("v_cvt_pk_bf16_f32 %0, %1, %2" : "=v"(r) : "v"(lo), "v"(hi));
    return r;
}
__device__ __forceinline__ void pswap(uint& a, uint& b) {
    asm("v_permlane32_swap_b32 %0, %1" : "+v"(a), "+v"(b));
}
// ---- packed f32 math via COMPILER vector ops (R19 post-mortem: hand-written
// v_pk_*_f32 asm without explicit op_sel_hi corrupted the .y half. Let LLVM
// emit pk-f32 with correct modifiers; falls back to scalar pairs if absent.)
__device__ __forceinline__ pkf pk_fma(pkf a, pkf b, pkf c) {
    return __builtin_elementwise_fma(a, b, c);
}
__device__ __forceinline__ pkf pk_mul(pkf a, pkf b) { return a * b; }
__device__ __forceinline__ pkf pk_add(pkf a, pkf b) { return a + b; }
__device__ __forceinline__ pkf mkpk(float a, float b) { pkf r; r.x = a; r.y = b; return r; }

// deg-5 log1p(e), e in (0,1]
#define LOG1P_PK(E) pk_mul((E), pk_fma((E), pk_fma((E), pk_fma((E), \
    pk_fma((E), kP4, kP3), kP2), kP1), kP0))
// 1/u on [1,2]: seed + 2 Newton
#define RCP12_PK(U, R) { R = pk_fma((U), kRMH, kRC); \
    R = pk_mul(R, pk_fma(pk_mul((U), R), kRM1, kR2)); \
    R = pk_mul(R, pk_fma(pk_mul((U), R), kRM1, kR2)); }
// softplus+sigmoid, x >= 0 guaranteed
#define SPSIG_POS_PK(X, SP, SG) { \
    pkf e_ = mkpk(__expf(-(X).x), __expf(-(X).y)); \
    pkf oe_ = pk_add(e_, kC1); \
    RCP12_PK(oe_, SG) \
    SP = pk_add((X), LOG1P_PK(e_)); }
// general sign softplus+sigmoid
#define SPSIG_GEN_PK(X, SP, SG) { \
    pkf e_ = mkpk(__expf(-fabsf((X).x)), __expf(-fabsf((X).y))); \
    pkf oe_ = pk_add(e_, kC1); \
    pkf r_; RCP12_PK(oe_, r_) \
    pkf er_ = pk_mul(e_, r_); \
    SG.x = (X).x >= 0.0f ? r_.x : er_.x; \
    SG.y = (X).y >= 0.0f ? r_.y : er_.y; \
    pkf l_ = LOG1P_PK(e_); \
    SP.x = fmaxf((X).x, 0.0f) + l_.x; \
    SP.y = fmaxf((X).y, 0.0f) + l_.y; }
#define SIG_GEN_PK(X, SG) { \
    pkf e_ = mkpk(__expf(-fabsf((X).x)), __expf(-fabsf((X).y))); \
    pkf oe_ = pk_add(e_, kC1); \
    pkf r_; RCP12_PK(oe_, r_) \
    pkf er_ = pk_mul(e_, r_); \
    SG.x = (X).x >= 0.0f ? r_.x : er_.x; \
    SG.y = (X).y >= 0.0f ? r_.y : er_.y; }

// ---------------- prep: weight tables + aout + cref --------------------------
__global__ __launch_bounds__(256) void icnn_prep(
    const float* __restrict__ rawA0, const float* __restrict__ rawA1,
    const float* __restrict__ rawAout,
    const float* __restrict__ W1,  const float* __restrict__ b1,
    const float* __restrict__ Wc0, const float* __restrict__ bc0,
    const float* __restrict__ Wc1, const float* __restrict__ bc1,
    const float* __restrict__ wout)
{
    __shared__ float sA0[1024], sA1[1024], sAout[32];
    const int t = threadIdx.x;
    for (int k = t; k < 1024; k += 256) sA0[k] = sp_only(rawA0[k]);
    for (int k = t; k < 1024; k += 256) sA1[k] = sp_only(rawA1[k]);
    if (t < 32) { float v = sp_only(rawAout[t]); sAout[t] = v; g_tab[t] = v; }
    __syncthreads();

    for (int k = t; k < 8192; k += 256) {
        int m = k >> 11, r = k & 2047;
        int hl = r >> 10, c = (r >> 9) & 1, l = (r >> 3) & 63, b = r & 7;
        int row = l & 31, j = 16 * c + 8 * (l >> 5) + b;
        float v;
        if      (m == 0) v = sA0[row * 32 + j];
        else if (m == 1) v = sA1[row * 32 + j];
        else if (m == 2) v = sA1[j * 32 + row];     // A1^T
        else             v = sA0[j * 32 + row];     // A0^T
        uint hi = bf16u(v);
        g_wt[m][hl][c][l][b] = (ushort)(hl == 0 ? hi : bf16u(v - bf16f(hi)));
    }

    // pair-transposed preact tables
    for (int k = t; k < 32; k += 256) {            // c0/c1, OFF-layout pairs
        int m = k >> 4, h = (k >> 3) & 1, q = k & 7;
        int e = 2 * q, off = (e & 3) + 8 * (e >> 2);
        int u0 = 4 * h + off, u1 = u0 + 1;
        const float* Wm = m ? Wc1 : Wc0;
        const float* Bm = m ? bc1 : bc0;
        g_pp[m][h][q][0] = Wm[2 * u0];     g_pp[m][h][q][1] = Wm[2 * u1];
        g_pp[m][h][q][2] = Wm[2 * u0 + 1]; g_pp[m][h][q][3] = Wm[2 * u1 + 1];
        g_pp[m][h][q][4] = Bm[u0];         g_pp[m][h][q][5] = Bm[u1];
        g_pp[m][h][q][6] = 0.0f;           g_pp[m][h][q][7] = 0.0f;
    }
    for (int k = t; k < 16; k += 256) {            // W1/b1, j-layout pairs
        int c = k >> 3, h = (k >> 2) & 1, s = k & 3;
        int j0 = 16 * c + 8 * h + 2 * s, j1 = j0 + 1;
        g_pA[c][h][s][0] = W1[2 * j0];     g_pA[c][h][s][1] = W1[2 * j1];
        g_pA[c][h][s][2] = W1[2 * j0 + 1]; g_pA[c][h][s][3] = W1[2 * j1 + 1];
        g_pA[c][h][s][4] = b1[j0];         g_pA[c][h][s][5] = b1[j1];
        g_pA[c][h][s][6] = 0.0f;           g_pA[c][h][s][7] = 0.0f;
    }

    // cref: exact fp32 gradient dW/dI1 at z0 = 0 (wave-0 lanes 0..31)
    if (t < 32) {
        const int i = t;
        float sa, sc0v;
        float zi = sp_sig(b1[i], sa);
        float u = 0.0f;
        for (int j = 0; j < 32; j++) u = fmaf(sA0[i * 32 + j], __shfl(zi, j, 64), u);
        float su; float t0 = sp_sig(u, su);
        float d0 = kAct2 * t0 * su;
        float spc = sp_sig(bc0[i], sc0v);
        float zn = fmaf(kActScale * t0, t0, spc);
        float u1 = 0.0f;
        for (int j = 0; j < 32; j++) u1 = fmaf(sA1[i * 32 + j], __shfl(zn, j, 64), u1);
        float su1; float t1 = sp_sig(u1, su1);
        float d1 = sAout[i] * kAct2 * t1 * su1;
        float contrib = Wc1[2 * i] * sAout[i] * sig_only(bc1[i]);
        float g = 0.0f;
        for (int j = 0; j < 32; j++) g = fmaf(sA1[j * 32 + i], __shfl(d1, j, 64), g);
        contrib = fmaf(Wc0[2 * i], g * sc0v, contrib);
        float gu0 = g * d0;
        float ga = 0.0f;
        for (int j = 0; j < 32; j++) ga = fmaf(sA0[j * 32 + i], __shfl(gu0, j, 64), ga);
        ga *= sa;
        contrib = fmaf(W1[2 * i], ga, contrib);
        for (int off = 16; off >= 1; off >>= 1)
            contrib += __shfl_down(contrib, off, 32);
        if (i == 0) g_tab[32] = wout[0] + contrib;
    }
}

// weight A-frag load (pure SSA, 16B aligned)
__device__ __forceinline__ s8b ldwt(int m, int hl, int c, int lane) {
    const uint_ma* p = (const uint_ma*)&g_wt[m][hl][c][lane][0];
    uint4v q; q.x = p[0]; q.y = p[1]; q.z = p[2]; q.w = p[3];
    return __builtin_bit_cast(s8b, q);
}

#define OFF(e) (((e) & 3) + 8 * ((e) >> 2))

// cross-half exchange via permlane32_swap (4 VALU ops)
#define SWAPJ(PZ, FA, FB) { \
    uint s0 = PZ[0], s1 = PZ[1], s2 = PZ[2], s3 = PZ[3]; \
    uint s4 = PZ[4], s5 = PZ[5], s6 = PZ[6], s7 = PZ[7]; \
    pswap(s0, s2); pswap(s1, s3); pswap(s4, s6); pswap(s5, s7); \
    uint4v qa, qb; \
    qa.x = s0; qa.y = s1; qa.z = s2; qa.w = s3; \
    qb.x = s4; qb.y = s5; qb.z = s6; qb.w = s7; \
    FA = __builtin_bit_cast(s8b, qa); FB = __builtin_bit_cast(s8b, qb); }

// 4-mfma matvec: acc += (Whi + Wlo) x B, K=32 via 2 chained chunks
#define MM(m, BA, BB, ACC) { \
    ACC = __builtin_amdgcn_mfma_f32_32x32x16_bf16(ldwt(m, 0, 0, lane), BA, ACC, 0, 0, 0); \
    ACC = __builtin_amdgcn_mfma_f32_32x32x16_bf16(ldwt(m, 0, 1, lane), BB, ACC, 0, 0, 0); \
    ACC = __builtin_amdgcn_mfma_f32_32x32x16_bf16(ldwt(m, 1, 0, lane), BA, ACC, 0, 0, 0); \
    ACC = __builtin_amdgcn_mfma_f32_32x32x16_bf16(ldwt(m, 1, 1, lane), BB, ACC, 0, 0, 0); }

// ---------------- main: weights-as-A MFMA + paired-f32 VALU ------------------
// R17 structure (LDS sigma carry, 1 tile/wave); all pairable VALU work on
// float2 vector ops (compiler-lowered pk-f32 where available).
__global__ __launch_bounds__(256) void icnn_main(
    const float* __restrict__ eps,
    const float* __restrict__ W1,  const float* __restrict__ b1,
    const float* __restrict__ Wc0, const float* __restrict__ bc0,
    const float* __restrict__ Wc1, const float* __restrict__ bc1,
    const float* __restrict__ wout,
    float* __restrict__ out)
{
    __shared__ uint carr[4][2][544];              // 17408 B: [wave][sigA|sigC0]
    const int tid  = threadIdx.x;
    const int lane = tid & 63, wib = tid >> 6;
    const bool hb_ = lane >= 32;
    const int  hB  = hb_ ? 1 : 0;
    const int  rowl = lane & 31;
    const long rowg = ((long)blockIdx.x * 4 + wib) * 32 + rowl;
    uint* __restrict__ ca = &carr[wib][0][0];     // sigma(a)
    uint* __restrict__ cc = &carr[wib][1][0];     // sigma(c0)

    const float e11 = eps[rowg * 3 + 0];
    const float e22 = eps[rowg * 3 + 1];
    const float e12 = eps[rowg * 3 + 2];
    const float x1 = e11 + e22;
    const float x2 = e11 * e11 + 2.0f * e12 * e12 + e22 * e22;

    const float wout0 = wout[0], wout1 = wout[1];
    const float cref  = g_tab[32];
    const char* W1c  = (const char*)W1;
    const char* Wc0c = (const char*)Wc0;
    const char* Wc1c = (const char*)Wc1;
    const char* aoc  = (const char*)&g_tab[0];

    const pkf kC1  = {1.0f, 1.0f};
    const pkf kRM1 = {-1.0f, -1.0f};
    const pkf kR2  = {2.0f, 2.0f};
    const pkf kRMH = {-0.5f, -0.5f};
    const pkf kRC  = {1.4571068f, 1.4571068f};
    const pkf kP4  = {0.03215845f, 0.03215845f};
    const pkf kP3  = {-0.13606275f, -0.13606275f};
    const pkf kP2  = {0.28947478f, 0.28947478f};
    const pkf kP1  = {-0.49190896f, -0.49190896f};
    const pkf kP0  = {0.99949556f, 0.99949556f};
    const pkf kA2  = {kAct2, kAct2};
    const pkf kAS  = {kActScale, kActScale};
    const pkf x1p  = {x1, x1};
    const pkf x2p  = {x2, x2};

    // ---- Stage A: z = sp(a); sigma(a) -> LDS carry
    uint zf[2][4];
    #pragma unroll
    for (int c = 0; c < 2; ++c)
    #pragma unroll
    for (int s = 0; s < 4; ++s) {
        const pkf w1p = *(const pkf*)&g_pA[c][hB][s][0];
        const pkf w2p = *(const pkf*)&g_pA[c][hB][s][2];
        const pkf bp  = *(const pkf*)&g_pA[c][hB][s][4];
        pkf a_ = pk_fma(w1p, x1p, pk_fma(w2p, x2p, bp));
        pkf z_, sg_;
        SPSIG_GEN_PK(a_, z_, sg_)
        zf[c][s] = cvt_pk_bf16(z_.x, z_.y);
        ca[rowl * 17 + 8 * c + 4 * hB + s] = cvt_pk_bf16(sg_.x, sg_.y);
    }
    uint4v zq0, zq1;
    zq0.x = zf[0][0]; zq0.y = zf[0][1]; zq0.z = zf[0][2]; zq0.w = zf[0][3];
    zq1.x = zf[1][0]; zq1.y = zf[1][1]; zq1.z = zf[1][2]; zq1.w = zf[1][3];
    s8b fA = __builtin_bit_cast(s8b, zq0);
    s8b fB = __builtin_bit_cast(s8b, zq1);

    // ---- matvec 0: u0 = A0 z
    f32x16 acc = {};
    MM(0, fA, fB, acc)

    // ---- Stage B: d0, zn (u0 >= 0); sigma(c0) -> LDS carry
    uint pd0[8], pzn[8];
    #pragma unroll
    for (int q = 0; q < 8; ++q) {
        const int e = 2 * q;
        pkf u_ = mkpk(acc[e], acc[e + 1]);
        pkf t_, su_;
        SPSIG_POS_PK(u_, t_, su_)
        pkf d0_ = pk_mul(kA2, pk_mul(t_, su_));
        pd0[q] = cvt_pk_bf16(d0_.x, d0_.y);
        const pkf w1p = *(const pkf*)&g_pp[0][hB][q][0];
        const pkf w2p = *(const pkf*)&g_pp[0][hB][q][2];
        const pkf bp  = *(const pkf*)&g_pp[0][hB][q][4];
        pkf c0_ = pk_fma(w1p, x1p, pk_fma(w2p, x2p, bp));
        pkf spc_, sc_;
        SPSIG_GEN_PK(c0_, spc_, sc_)
        cc[rowl * 17 + 2 * hB + (OFF(e) >> 1)] = cvt_pk_bf16(sc_.x, sc_.y);
        pkf zn_ = pk_fma(pk_mul(kAS, t_), t_, spc_);
        pzn[q] = cvt_pk_bf16(zn_.x, zn_.y);
    }
    SWAPJ(pzn, fA, fB)

    // ---- matvec 1: u1 = A1 zn
    f32x16 acc1 = {};
    MM(1, fA, fB, acc1)

    // ---- Stage C: T1 fold (c1-skip, packed (g0,gq)) + d1 (u1 >= 0)
    pkf gpk = {0.0f, 0.0f};
    uint pdd[8];
    #pragma unroll
    for (int q = 0; q < 8; ++q) {
        const int e = 2 * q, off = OFF(e);
        const pkf w1p = *(const pkf*)&g_pp[1][hB][q][0];
        const pkf w2p = *(const pkf*)&g_pp[1][hB][q][2];
        const pkf bp  = *(const pkf*)&g_pp[1][hB][q][4];
        pkf c1_ = pk_fma(w1p, x1p, pk_fma(w2p, x2p, bp));
        pkf sg_;
        SIG_GEN_PK(c1_, sg_)
        const pkf aop = *(const pkf*)(aoc + 16 * hB + 4 * off);
        pkf w_ = pk_mul(aop, sg_);
        const pkf wxy = *(const pkf*)(Wc1c + 32 * hB + 8 * off);
        const pkf wzw = *(const pkf*)(Wc1c + 32 * hB + 8 * off + 8);
        gpk = pk_fma(wxy, mkpk(w_.x, w_.x), gpk);
        gpk = pk_fma(wzw, mkpk(w_.y, w_.y), gpk);
        pkf u_ = mkpk(acc1[e], acc1[e + 1]);
        pkf t_, su_;
        SPSIG_POS_PK(u_, t_, su_)
        pkf d1_ = pk_mul(aop, pk_mul(kA2, pk_mul(t_, su_)));
        pdd[q] = cvt_pk_bf16(d1_.x, d1_.y);
    }
    SWAPJ(pdd, fA, fB)

    // ---- matvec 2: g = A1^T d1 (raw f32 in acc2)
    f32x16 acc2 = {};
    MM(2, fA, fB, acc2)

    // ---- T2 fold: sigma(c0) from LDS carry + gg = g*d0
    uint pgg[8];
    #pragma unroll
    for (int q = 0; q < 8; ++q) {
        const int e = 2 * q, off = OFF(e);
        uint pk_ = cc[rowl * 17 + 2 * hB + (off >> 1)];
        pkf sg_ = mkpk(__uint_as_float(pk_ << 16), __uint_as_float(pk_ & 0xFFFF0000u));
        pkf a2_ = mkpk(acc2[e], acc2[e + 1]);
        pkf t_ = pk_mul(a2_, sg_);
        const pkf wxy = *(const pkf*)(Wc0c + 32 * hB + 8 * off);
        const pkf wzw = *(const pkf*)(Wc0c + 32 * hB + 8 * off + 8);
        gpk = pk_fma(wxy, mkpk(t_.x, t_.x), gpk);
        gpk = pk_fma(wzw, mkpk(t_.y, t_.y), gpk);
        pkf d0_ = mkpk(__uint_as_float(pd0[q] << 16), __uint_as_float(pd0[q] & 0xFFFF0000u));
        pkf gg_ = pk_mul(a2_, d0_);
        pgg[q] = cvt_pk_bf16(gg_.x, gg_.y);
    }
    SWAPJ(pgg, fA, fB)

    // ---- matvec 3: A0^T gg
    f32x16 acc3 = {};
    MM(3, fA, fB, acc3)

    // ---- T3 fold: sigma(a) from LDS carry
    #pragma unroll
    for (int q = 0; q < 8; ++q) {
        const int e = 2 * q, off = OFF(e);
        uint pk_ = ca[rowl * 17 + 2 * hB + (off >> 1)];
        pkf sg_ = mkpk(__uint_as_float(pk_ << 16), __uint_as_float(pk_ & 0xFFFF0000u));
        pkf a3_ = mkpk(acc3[e], acc3[e + 1]);
        pkf t_ = pk_mul(a3_, sg_);
        const pkf wxy = *(const pkf*)(W1c + 32 * hB + 8 * off);
        const pkf wzw = *(const pkf*)(W1c + 32 * hB + 8 * off + 8);
        gpk = pk_fma(wxy, mkpk(t_.x, t_.x), gpk);
        gpk = pk_fma(wzw, mkpk(t_.y, t_.y), gpk);
    }

    float g0p = gpk.x, gqp = gpk.y;

    // ---- cross-half reduce via permlane32_swap; lanes < 32 write their row
    uint ga_ = __float_as_uint(g0p), gb_ = ga_;
    pswap(ga_, gb_);
    float g0o = __uint_as_float(hb_ ? ga_ : gb_);
    uint qa_ = __float_as_uint(gqp), qb_ = qa_;
    pswap(qa_, qb_);
    float gqo = __uint_as_float(hb_ ? qa_ : qb_);

    float g0f = wout0 + g0p + g0o;
    float gqf = wout1 + gqp + gqo;
    const float dI1 = g0f - cref;
    const float dI2 = gqf;
    if (!hb_) {
        out[rowg * 3 + 0] = fmaf(2.0f * e11, dI2, dI1);
        out[rowg * 3 + 1] = fmaf(2.0f * e22, dI2, dI1);
        out[rowg * 3 + 2] = 2.0f * e12 * dI2;
    }
}

extern "C" void kernel_launch(void* const* d_in, const int* in_sizes, int n_in,
                              void* d_out, int out_size, void* d_ws, size_t ws_size,
                              hipStream_t stream)
{
    (void)in_sizes; (void)n_in; (void)out_size; (void)d_ws; (void)ws_size;
    const float* eps    = (const float*)d_in[0];
    const float* W1     = (const float*)d_in[1];
    const float* b1     = (const float*)d_in[2];
    const float* rawA0  = (const float*)d_in[3];
    const float* rawA1  = (const float*)d_in[4];
    const float* Wc0    = (const float*)d_in[5];
    const float* bc0    = (const float*)d_in[6];
    const float* Wc1    = (const float*)d_in[7];
    const float* bc1    = (const float*)d_in[8];
    const float* rawAout= (const float*)d_in[9];
    const float* wout   = (const float*)d_in[10];
    float* out = (float*)d_out;

    icnn_prep<<<1, 256, 0, stream>>>(rawA0, rawA1, rawAout, W1, b1, Wc0, bc0, Wc1, bc1, wout);
    icnn_main<<<kBatch / 128, 256, 0, stream>>>(eps, W1, b1, Wc0, bc0, Wc1, bc1, wout, out);
}

// Round 22
// 189.044 us; speedup vs baseline: 1.1131x; 1.1131x over previous
//
#include <hip/hip_runtime.h>

typedef __attribute__((ext_vector_type(8)))  short s8b;    // 8 x bf16
typedef __attribute__((ext_vector_type(16))) float f32x16; // mfma C/D
typedef __attribute__((ext_vector_type(4)))  uint  uint4v;
typedef uint __attribute__((may_alias)) uint_ma;

static constexpr int   kBatch    = 2097152;
static constexpr float kActScale = 1.0f / 12.0f;
static constexpr float kAct2     = 1.0f / 6.0f;   // 2*ACT_SCALE

// fp32 table: [0,32) aout ; [32] cref
__device__ float g_tab[40];
// Weight A-frag tables, per matvec m: lane l holds W_m[row=l&31][j=16c+8*(l>>5)+b]
__device__ __attribute__((aligned(16))) ushort g_wt[4][2][2][64][8];
// Preact A-frag tables, set m: 0={W1,b1} 1={Wc0,bc0} 2={Wc1,bc1}.
// Cross-term K-packing (half0): [w1h, w1h, w1l, w2h, w2h, w2l, bh, bl]
// pairs with B = [x1h, x1l, x1h, x2h, x2l, x2h, 1, 1]  -> exact to 2^-18.
__device__ __attribute__((aligned(16))) ushort g_pt[3][64][8];

__device__ __forceinline__ float rcp_f(float x) { return __fdividef(1.0f, x); }
__device__ __forceinline__ float sp_only(float x) {
    float e = __expf(-fabsf(x));
    return fmaxf(x, 0.0f) + __logf(1.0f + e);
}
__device__ __forceinline__ float sig_only(float x) {
    float e = __expf(-fabsf(x));
    float r = rcp_f(1.0f + e);
    return (x >= 0.0f) ? r : e * r;
}
__device__ __forceinline__ float sp_sig(float x, float& sig) {
    float e  = __expf(-fabsf(x));
    float oe = 1.0f + e;
    float r  = rcp_f(oe);
    sig = (x >= 0.0f) ? r : e * r;
    return fmaxf(x, 0.0f) + __logf(oe);
}

// ---- trans-diet versions (main kernel only) ----
// deg-5 log1p(e), e in (0,1], |err| <= 1e-5
__device__ __forceinline__ float log1p_e(float e) {
    return e * fmaf(e, fmaf(e, fmaf(e, fmaf(e, 0.03215845f, -0.13606275f),
                                    0.28947478f), -0.49190896f), 0.99949556f);
}
// 1/u on [1,2]: seed + TWO Newton steps (rel err 1.3e-5). R21 post-mortem:
// 1-Newton is 7.4e-3 rel (seed rel err 8.6e-2 squared), 4x bf16 rounding,
// and T1 consumes sigma in raw f32 -> absmax blew to 2048. Two steps proven
// in R17 at absmax 768.
__device__ __forceinline__ float rcp12(float u) {
    float r = fmaf(u, -0.5f, 1.4571068f);
    r = r * fmaf(-u, r, 2.0f);
    r = r * fmaf(-u, r, 2.0f);
    return r;
}
__device__ __forceinline__ float sp_sig_p(float x, float& sig) {
    float e = __expf(-fabsf(x));
    float r = rcp12(1.0f + e);
    sig = (x >= 0.0f) ? r : e * r;
    return fmaxf(x, 0.0f) + log1p_e(e);
}
// x >= 0 guaranteed (u0, u1 are sums of positive products)
__device__ __forceinline__ float sp_sig_pos(float x, float& sig) {
    float e = __expf(-x);
    sig = rcp12(1.0f + e);
    return x + log1p_e(e);
}
__device__ __forceinline__ float sig_only_p(float x) {
    float e = __expf(-fabsf(x));
    float r = rcp12(1.0f + e);
    return (x >= 0.0f) ? r : e * r;
}

__device__ __forceinline__ uint  bf16u(float x) {
    uint u = __float_as_uint(x);
    return (u + 0x7FFFu + ((u >> 16) & 1u)) >> 16;      // RNE
}
__device__ __forceinline__ float bf16f(uint h) { return __uint_as_float(h << 16); }
__device__ __forceinline__ uint cvt_pk_bf16(float lo, float hi) {
    uint r;
    asm("v_cvt_pk_bf16_f32 %0, %1, %2" : "=v"(r) : "v"(lo), "v"(hi));
    return r;
}
__device__ __forceinline__ void pswap(uint& a, uint& b) {
    asm("v_permlane32_swap_b32 %0, %1" : "+v"(a), "+v"(b));
}

// ---------------- prep: weight tables + aout + cref --------------------------
__global__ __launch_bounds__(256) void icnn_prep(
    const float* __restrict__ rawA0, const float* __restrict__ rawA1,
    const float* __restrict__ rawAout,
    const float* __restrict__ W1,  const float* __restrict__ b1,
    const float* __restrict__ Wc0, const float* __restrict__ bc0,
    const float* __restrict__ Wc1, const float* __restrict__ bc1,
    const float* __restrict__ wout)
{
    __shared__ float sA0[1024], sA1[1024], sAout[32];
    const int t = threadIdx.x;
    for (int k = t; k < 1024; k += 256) sA0[k] = sp_only(rawA0[k]);
    for (int k = t; k < 1024; k += 256) sA1[k] = sp_only(rawA1[k]);
    if (t < 32) { float v = sp_only(rawAout[t]); sAout[t] = v; g_tab[t] = v; }
    __syncthreads();

    // matvec A-frag tables
    for (int k = t; k < 8192; k += 256) {
        int m = k >> 11, r = k & 2047;
        int hl = r >> 10, c = (r >> 9) & 1, l = (r >> 3) & 63, b = r & 7;
        int row = l & 31, j = 16 * c + 8 * (l >> 5) + b;
        float v;
        if      (m == 0) v = sA0[row * 32 + j];
        else if (m == 1) v = sA1[row * 32 + j];
        else if (m == 2) v = sA1[j * 32 + row];     // A1^T
        else             v = sA0[j * 32 + row];     // A0^T
        uint hi = bf16u(v);
        g_wt[m][hl][c][l][b] = (ushort)(hl == 0 ? hi : bf16u(v - bf16f(hi)));
    }

    // preact A-frag tables (cross-term K-packing, half0 only)
    for (int k = t; k < 1536; k += 256) {
        int m = k >> 9, r = k & 511, l = r >> 3, b = r & 7;
        int unit = l & 31, half = l >> 5;
        ushort v = 0;
        if (half == 0) {
            const float* Wm = (m == 0) ? W1 : ((m == 1) ? Wc0 : Wc1);
            const float* Bm = (m == 0) ? b1 : ((m == 1) ? bc0 : bc1);
            float w1 = Wm[2 * unit], w2 = Wm[2 * unit + 1], bb = Bm[unit];
            uint h;
            switch (b) {
                case 0: v = (ushort)bf16u(w1); break;                              // w1h (x1h)
                case 1: v = (ushort)bf16u(w1); break;                              // w1h (x1l)
                case 2: h = bf16u(w1); v = (ushort)bf16u(w1 - bf16f(h)); break;    // w1l (x1h)
                case 3: v = (ushort)bf16u(w2); break;                              // w2h (x2h)
                case 4: v = (ushort)bf16u(w2); break;                              // w2h (x2l)
                case 5: h = bf16u(w2); v = (ushort)bf16u(w2 - bf16f(h)); break;    // w2l (x2h)
                case 6: v = (ushort)bf16u(bb); break;                              // bh (1)
                case 7: h = bf16u(bb); v = (ushort)bf16u(bb - bf16f(h)); break;    // bl (1)
            }
        }
        g_pt[m][l][b] = v;
    }

    // cref: exact fp32 gradient dW/dI1 at z0 = 0 (wave-0 lanes 0..31)
    if (t < 32) {
        const int i = t;
        float sa, sc0v;
        float zi = sp_sig(b1[i], sa);
        float u = 0.0f;
        for (int j = 0; j < 32; j++) u = fmaf(sA0[i * 32 + j], __shfl(zi, j, 64), u);
        float su; float t0 = sp_sig(u, su);
        float d0 = kAct2 * t0 * su;
        float spc = sp_sig(bc0[i], sc0v);
        float zn = fmaf(kActScale * t0, t0, spc);
        float u1 = 0.0f;
        for (int j = 0; j < 32; j++) u1 = fmaf(sA1[i * 32 + j], __shfl(zn, j, 64), u1);
        float su1; float t1 = sp_sig(u1, su1);
        float d1 = sAout[i] * kAct2 * t1 * su1;
        float contrib = Wc1[2 * i] * sAout[i] * sig_only(bc1[i]);
        float g = 0.0f;
        for (int j = 0; j < 32; j++) g = fmaf(sA1[j * 32 + i], __shfl(d1, j, 64), g);
        contrib = fmaf(Wc0[2 * i], g * sc0v, contrib);
        float gu0 = g * d0;
        float ga = 0.0f;
        for (int j = 0; j < 32; j++) ga = fmaf(sA0[j * 32 + i], __shfl(gu0, j, 64), ga);
        ga *= sa;
        contrib = fmaf(W1[2 * i], ga, contrib);
        for (int off = 16; off >= 1; off >>= 1)
            contrib += __shfl_down(contrib, off, 32);
        if (i == 0) g_tab[32] = wout[0] + contrib;
    }
}

// frag loads (pure SSA, 16B aligned)
__device__ __forceinline__ s8b ldwt(int m, int hl, int c, int lane) {
    const uint_ma* p = (const uint_ma*)&g_wt[m][hl][c][lane][0];
    uint4v q; q.x = p[0]; q.y = p[1]; q.z = p[2]; q.w = p[3];
    return __builtin_bit_cast(s8b, q);
}
__device__ __forceinline__ s8b ldpt(int m, int lane) {
    const uint_ma* p = (const uint_ma*)&g_pt[m][lane][0];
    uint4v q; q.x = p[0]; q.y = p[1]; q.z = p[2]; q.w = p[3];
    return __builtin_bit_cast(s8b, q);
}

// i-offset of C-frag element e (unit = 4*half + OFF(e))
#define OFF(e) (((e) & 3) + 8 * ((e) >> 2))

// cross-half exchange via permlane32_swap (4 VALU ops)
#define SWAPJ(PZ, FA, FB) { \
    uint s0 = PZ[0], s1 = PZ[1], s2 = PZ[2], s3 = PZ[3]; \
    uint s4 = PZ[4], s5 = PZ[5], s6 = PZ[6], s7 = PZ[7]; \
    pswap(s0, s2); pswap(s1, s3); pswap(s4, s6); pswap(s5, s7); \
    uint4v qa, qb; \
    qa.x = s0; qa.y = s1; qa.z = s2; qa.w = s3; \
    qb.x = s4; qb.y = s5; qb.z = s6; qb.w = s7; \
    FA = __builtin_bit_cast(s8b, qa); FB = __builtin_bit_cast(s8b, qb); }

// 4-mfma matvec: acc += (Whi + Wlo) x B, K=32 via 2 chained chunks
#define MM(m, BA, BB, ACC) { \
    ACC = __builtin_amdgcn_mfma_f32_32x32x16_bf16(ldwt(m, 0, 0, lane), BA, ACC, 0, 0, 0); \
    ACC = __builtin_amdgcn_mfma_f32_32x32x16_bf16(ldwt(m, 0, 1, lane), BB, ACC, 0, 0, 0); \
    ACC = __builtin_amdgcn_mfma_f32_32x32x16_bf16(ldwt(m, 1, 0, lane), BA, ACC, 0, 0, 0); \
    ACC = __builtin_amdgcn_mfma_f32_32x32x16_bf16(ldwt(m, 1, 1, lane), BB, ACC, 0, 0, 0); }

// ---------------- main: weights-as-A MFMA, zero LDS, preact-MFMAs ------------
// R17 numerics (2-Newton rcp12) + R21 structure: preacts a/c0/c1 via 3
// interleaved MFMAs (<= 2 f32x16 live at once) in the OFF layout the stages
// consume -> sigma carries in registers, LDS = 0.
__global__ __launch_bounds__(256) void icnn_main(
    const float* __restrict__ eps,
    const float* __restrict__ W1,  const float* __restrict__ b1,
    const float* __restrict__ Wc0, const float* __restrict__ bc0,
    const float* __restrict__ Wc1, const float* __restrict__ bc1,
    const float* __restrict__ wout,
    float* __restrict__ out)
{
    const int tid  = threadIdx.x;
    const int lane = tid & 63, wib = tid >> 6;
    const bool hb_ = lane >= 32;
    const int  hB  = hb_ ? 1 : 0;
    const int  rowl = lane & 31;
    const long rowg = ((long)blockIdx.x * 4 + wib) * 32 + rowl;

    const float e11 = eps[rowg * 3 + 0];
    const float e22 = eps[rowg * 3 + 1];
    const float e12 = eps[rowg * 3 + 2];
    const float x1 = e11 + e22;
    const float x2 = e11 * e11 + 2.0f * e12 * e12 + e22 * e22;

    const float wout0 = wout[0], wout1 = wout[1];
    const float cref  = g_tab[32];
    const char* W1c  = (const char*)W1;
    const char* Wc0c = (const char*)Wc0;
    const char* Wc1c = (const char*)Wc1;
    const char* aoc  = (const char*)&g_tab[0];

    float g0p = 0.0f, gqp = 0.0f;

    // ---- preact B-frag: [x1h, x1l, x1h, x2h, x2l, x2h, 1, 1] (half0 only)
    uint x1h = bf16u(x1);
    uint x1l = bf16u(x1 - bf16f(x1h));
    uint x2h = bf16u(x2);
    uint x2l = bf16u(x2 - bf16f(x2h));
    uint4v bq;
    bq.x = hb_ ? 0u : (x1h | (x1l << 16));
    bq.y = hb_ ? 0u : (x1h | (x2h << 16));
    bq.z = hb_ ? 0u : (x2l | (x2h << 16));
    bq.w = hb_ ? 0u : 0x3F803F80u;
    s8b bx = __builtin_bit_cast(s8b, bq);
    const f32x16 zzz = {};

    // ---- Stage A: a via MFMA; z = sp(a); sigma(a) -> registers (psa)
    f32x16 pa = __builtin_amdgcn_mfma_f32_32x32x16_bf16(ldpt(0, lane), bx, zzz, 0, 0, 0);
    uint pz[8], psa[8];
    #pragma unroll
    for (int q = 0; q < 8; ++q) {
        const int e = 2 * q;
        float s0, s1;
        float z0 = sp_sig_p(pa[e],     s0);
        float z1 = sp_sig_p(pa[e + 1], s1);
        pz[q]  = cvt_pk_bf16(z0, z1);
        psa[q] = cvt_pk_bf16(s0, s1);
    }
    s8b fA, fB;
    SWAPJ(pz, fA, fB)

    // ---- matvec 0: u0 = A0 z  (+ issue c0 preact MFMA alongside)
    f32x16 pc0 = __builtin_amdgcn_mfma_f32_32x32x16_bf16(ldpt(1, lane), bx, zzz, 0, 0, 0);
    f32x16 acc = {};
    MM(0, fA, fB, acc)

    // ---- Stage B: d0, zn (u0 >= 0); sigma(c0) -> registers (psc)
    uint pd0[8], psc[8];
    #pragma unroll
    for (int q = 0; q < 8; ++q) {
        const int e = 2 * q;
        float su;  float t  = sp_sig_pos(acc[e], su);
        float su2; float t2 = sp_sig_pos(acc[e + 1], su2);
        float sc0, sc1;
        float spc0 = sp_sig_p(pc0[e],     sc0);
        float spc1 = sp_sig_p(pc0[e + 1], sc1);
        psc[q] = cvt_pk_bf16(sc0, sc1);
        pd0[q] = cvt_pk_bf16(kAct2 * t * su, kAct2 * t2 * su2);
        pz[q]  = cvt_pk_bf16(fmaf(kActScale * t, t, spc0),
                             fmaf(kActScale * t2, t2, spc1));
    }
    SWAPJ(pz, fA, fB)

    // ---- matvec 1: u1 = A1 zn  (+ issue c1 preact MFMA alongside)
    f32x16 pc1 = __builtin_amdgcn_mfma_f32_32x32x16_bf16(ldpt(2, lane), bx, zzz, 0, 0, 0);
    f32x16 acc1 = {};
    MM(1, fA, fB, acc1)

    // ---- Stage C: T1 fold (c1-skip) + d1   (u1 >= 0)
    uint pdd[8];
    #pragma unroll
    for (int q = 0; q < 8; ++q) {
        const int e = 2 * q, off = OFF(e);
        const float* wc4 = (const float*)(Wc1c + 32 * hB + 8 * off);
        const float* ao2 = (const float*)(aoc  + 16 * hB + 4 * off);
        float wA = ao2[0] * sig_only_p(pc1[e]);
        float wB = ao2[1] * sig_only_p(pc1[e + 1]);
        g0p = fmaf(wc4[0], wA, g0p); gqp = fmaf(wc4[1], wA, gqp);
        g0p = fmaf(wc4[2], wB, g0p); gqp = fmaf(wc4[3], wB, gqp);
        float su;  float t  = sp_sig_pos(acc1[e], su);
        float su2; float t2 = sp_sig_pos(acc1[e + 1], su2);
        pdd[q] = cvt_pk_bf16(ao2[0] * kAct2 * t * su, ao2[1] * kAct2 * t2 * su2);
    }
    SWAPJ(pdd, fA, fB)

    // ---- matvec 2: g = A1^T d1 (raw f32 in acc2)
    f32x16 acc2 = {};
    MM(2, fA, fB, acc2)

    // ---- T2 fold: sigma(c0) from registers + gg = g*d0
    uint pgg[8];
    #pragma unroll
    for (int q = 0; q < 8; ++q) {
        const int e = 2 * q, off = OFF(e);
        const float* wc4 = (const float*)(Wc0c + 32 * hB + 8 * off);
        float tA = acc2[e]     * bf16f(psc[q] & 0xFFFFu);
        float tB = acc2[e + 1] * bf16f(psc[q] >> 16);
        g0p = fmaf(wc4[0], tA, g0p); gqp = fmaf(wc4[1], tA, gqp);
        g0p = fmaf(wc4[2], tB, g0p); gqp = fmaf(wc4[3], tB, gqp);
        pgg[q] = cvt_pk_bf16(acc2[e] * bf16f(pd0[q] & 0xFFFFu),
                             acc2[e + 1] * bf16f(pd0[q] >> 16));
    }
    SWAPJ(pgg, fA, fB)

    // ---- matvec 3: A0^T gg
    f32x16 acc3 = {};
    MM(3, fA, fB, acc3)

    // ---- T3 fold: sigma(a) from registers
    #pragma unroll
    for (int q = 0; q < 8; ++q) {
        const int e = 2 * q, off = OFF(e);
        const float* w4 = (const float*)(W1c + 32 * hB + 8 * off);
        float gA = acc3[e]     * bf16f(psa[q] & 0xFFFFu);
        float gB = acc3[e + 1] * bf16f(psa[q] >> 16);
        g0p = fmaf(w4[0], gA, g0p); gqp = fmaf(w4[1], gA, gqp);
        g0p = fmaf(w4[2], gB, g0p); gqp = fmaf(w4[3], gB, gqp);
    }

    // ---- cross-half reduce via permlane32_swap; lanes < 32 write their row
    uint ga_ = __float_as_uint(g0p), gb_ = ga_;
    pswap(ga_, gb_);
    float g0o = __uint_as_float(hb_ ? ga_ : gb_);
    uint qa_ = __float_as_uint(gqp), qb_ = qa_;
    pswap(qa_, qb_);
    float gqo = __uint_as_float(hb_ ? qa_ : qb_);

    float g0f = wout0 + g0p + g0o;
    float gqf = wout1 + gqp + gqo;
    const float dI1 = g0f - cref;
    const float dI2 = gqf;
    if (!hb_) {
        out[rowg * 3 + 0] = fmaf(2.0f * e11, dI2, dI1);
        out[rowg * 3 + 1] = fmaf(2.0f * e22, dI2, dI1);
        out[rowg * 3 + 2] = 2.0f * e12 * dI2;
    }
}

extern "C" void kernel_launch(void* const* d_in, const int* in_sizes, int n_in,
                              void* d_out, int out_size, void* d_ws, size_t ws_size,
                              hipStream_t stream)
{
    (void)in_sizes; (void)n_in; (void)out_size; (void)d_ws; (void)ws_size;
    const float* eps    = (const float*)d_in[0];
    const float* W1     = (const float*)d_in[1];
    const float* b1     = (const float*)d_in[2];
    const float* rawA0  = (const float*)d_in[3];
    const float* rawA1  = (const float*)d_in[4];
    const float* Wc0    = (const float*)d_in[5];
    const float* bc0    = (const float*)d_in[6];
    const float* Wc1    = (const float*)d_in[7];
    const float* bc1    = (const float*)d_in[8];
    const float* rawAout= (const float*)d_in[9];
    const float* wout   = (const float*)d_in[10];
    float* out = (float*)d_out;

    icnn_prep<<<1, 256, 0, stream>>>(rawA0, rawA1, rawAout, W1, b1, Wc0, bc0, Wc1, bc1, wout);
    icnn_main<<<kBatch / 128, 256, 0, stream>>>(eps, W1, b1, Wc0, bc0, Wc1, bc1, wout, out);
}